// Round 21
// baseline (1165.902 us; speedup 1.0000x reference)
//
#include <hip/hip_runtime.h>
#include <hip/hip_bf16.h>
#include <math.h>

// Problem constants
constexpr int BATCH = 8;
constexpr int NPTS  = 2048;
constexpr int CH    = 128;
constexpr int CHO   = 256;
constexpr int NCEN  = 512;
constexpr int NNEI  = 32;   // n_near
constexpr int NTOP  = 11;   // n_stepk + 1
constexpr int NW    = 64;   // bitset words per row (2048/32)
constexpr int SMEM_BYTES = 17408;   // gemm/top11/fps arena
constexpr int SMEM_MID   = 20608;   // reach arena (superset of gemm arena)

struct Ptr7 { const float* p[7]; };

// ---------------------------------------------------------------- xx = sum(x^2)
__global__ __launch_bounds__(256) void xx_kernel(const float* __restrict__ x,
                                                 float* __restrict__ xx) {
    int p = blockIdx.x * 256 + threadIdx.x;
    if (p >= BATCH * NPTS) return;
    const float4* xr = (const float4*)(x + (size_t)p * CH);
    float s = 0.f;
#pragma unroll
    for (int i = 0; i < CH / 4; i++) {
        float4 v = xr[i];
        s += v.x * v.x + v.y * v.y + v.z * v.z + v.w * v.w;
    }
    xx[p] = s;
}

// ---------------------------------------------------------------- D (symmetric: jt>=it tiles, mirrored; bitwise-faithful)
__global__ __launch_bounds__(256) void dmat_kernel(const float* __restrict__ x,
                                                   const float* __restrict__ xx,
                                                   float* __restrict__ D) {
    __shared__ __align__(16) char smem[SMEM_BYTES];
    int it = blockIdx.y, jt = blockIdx.x;
    if (jt < it) return;
    float (*As)[68] = (float(*)[68])smem;
    float (*Bs)[68] = (float(*)[68])(smem + 32 * 68 * 4);
    int bz = blockIdx.z;
    int i0 = it * 64, j0 = jt * 64;
    const float* X = x + (size_t)bz * NPTS * CH;
    int t = threadIdx.x, tx = t & 15, ty = t >> 4;
    int lr = t >> 3, lc = (t & 7) * 4;
    const float* ai0 = X + (size_t)(i0 + lr) * CH;
    const float* ai1 = X + (size_t)(i0 + lr + 32) * CH;
    const float* bj0 = X + (size_t)(j0 + lr) * CH;
    const float* bj1 = X + (size_t)(j0 + lr + 32) * CH;
    float acc[4][4] = {};
    for (int kc = 0; kc < CH; kc += 32) {
        float4 a0 = *(const float4*)(ai0 + kc + lc);
        float4 a1 = *(const float4*)(ai1 + kc + lc);
        float4 b0 = *(const float4*)(bj0 + kc + lc);
        float4 b1 = *(const float4*)(bj1 + kc + lc);
        __syncthreads();
        As[lc + 0][lr] = a0.x; As[lc + 1][lr] = a0.y; As[lc + 2][lr] = a0.z; As[lc + 3][lr] = a0.w;
        As[lc + 0][lr + 32] = a1.x; As[lc + 1][lr + 32] = a1.y; As[lc + 2][lr + 32] = a1.z; As[lc + 3][lr + 32] = a1.w;
        Bs[lc + 0][lr] = b0.x; Bs[lc + 1][lr] = b0.y; Bs[lc + 2][lr] = b0.z; Bs[lc + 3][lr] = b0.w;
        Bs[lc + 0][lr + 32] = b1.x; Bs[lc + 1][lr + 32] = b1.y; Bs[lc + 2][lr + 32] = b1.z; Bs[lc + 3][lr + 32] = b1.w;
        __syncthreads();
#pragma unroll
        for (int kk = 0; kk < 32; kk++) {
            float4 av = *(const float4*)&As[kk][ty * 4];
            float4 bv = *(const float4*)&Bs[kk][tx * 4];
            float a[4] = {av.x, av.y, av.z, av.w};
            float b[4] = {bv.x, bv.y, bv.z, bv.w};
#pragma unroll
            for (int i = 0; i < 4; i++)
#pragma unroll
                for (int j = 0; j < 4; j++) acc[i][j] += a[i] * b[j];
        }
    }
    const float* xxb = xx + bz * NPTS;
    float xi[4], xj[4];
#pragma unroll
    for (int i = 0; i < 4; i++) xi[i] = xxb[i0 + ty * 4 + i];
#pragma unroll
    for (int j = 0; j < 4; j++) xj[j] = xxb[j0 + tx * 4 + j];
    float ov[4][4];
#pragma unroll
    for (int i = 0; i < 4; i++)
#pragma unroll
        for (int j = 0; j < 4; j++) ov[i][j] = xi[i] + xj[j] - 2.f * acc[i][j];
#pragma unroll
    for (int i = 0; i < 4; i++) {
        float4 o = {ov[i][0], ov[i][1], ov[i][2], ov[i][3]};
        *(float4*)(D + ((size_t)bz * NPTS + i0 + ty * 4 + i) * NPTS + j0 + tx * 4) = o;
    }
    if (jt > it) {
        __syncthreads();
        float (*T)[65] = (float(*)[65])smem;
#pragma unroll
        for (int i = 0; i < 4; i++)
#pragma unroll
            for (int j = 0; j < 4; j++) T[ty * 4 + i][tx * 4 + j] = ov[i][j];
        __syncthreads();
#pragma unroll
        for (int i = 0; i < 4; i++) {
            float4 o;
            o.x = T[tx * 4 + 0][ty * 4 + i];
            o.y = T[tx * 4 + 1][ty * 4 + i];
            o.z = T[tx * 4 + 2][ty * 4 + i];
            o.w = T[tx * 4 + 3][ty * 4 + i];
            *(float4*)(D + ((size_t)bz * NPTS + j0 + ty * 4 + i) * NPTS + i0 + tx * 4) = o;
        }
    }
}

// ---------------------------------------------------------------- fused front: fps (blocks 0..7, 4 waves) + top-11 (blocks 8..)
__global__ __launch_bounds__(256) void fused_front_kernel(const float* __restrict__ D,
                                                          unsigned int* __restrict__ adj,
                                                          int* __restrict__ fps_idx) {
    __shared__ __align__(16) char smem[SMEM_BYTES];
    if (blockIdx.x < BATCH) {
        // ---------------- FPS: 4 waves; 8 elems/thread; 2-barrier cross-wave merge ----------------
        int t = threadIdx.x;
        int b = blockIdx.x;
        float2* red = (float2*)smem;               // 4 (v,j) pairs
        int* bc = (int*)(smem + 64);
        float mind[8];
#pragma unroll
        for (int r = 0; r < 8; r++) mind[r] = INFINITY;
        int prev = 0;
        if (t == 0) fps_idx[b * NCEN] = 0;
        const float* Db = D + (size_t)b * NPTS * NPTS;
        for (int s = 1; s < NCEN; s++) {
            const float4* rowp = (const float4*)(Db + (size_t)prev * NPTS);
            float4 g0 = rowp[t];
            float4 g1 = rowp[t + 256];
            float bv = -INFINITY; int bj = NPTS;
            // first quad: j = 4t..4t+3 (ascending; strict > keeps lowest idx)
            {
                int j0 = 4 * t;
                float m0 = fminf(mind[0], g0.x); mind[0] = m0;
                float m1 = fminf(mind[1], g0.y); mind[1] = m1;
                float m2 = fminf(mind[2], g0.z); mind[2] = m2;
                float m3 = fminf(mind[3], g0.w); mind[3] = m3;
                if (m0 > bv) { bv = m0; bj = j0 + 0; }
                if (m1 > bv) { bv = m1; bj = j0 + 1; }
                if (m2 > bv) { bv = m2; bj = j0 + 2; }
                if (m3 > bv) { bv = m3; bj = j0 + 3; }
            }
            // second quad: j = 4(t+256).. (ascending, > first quad)
            {
                int j0 = 4 * (t + 256);
                float m0 = fminf(mind[4], g1.x); mind[4] = m0;
                float m1 = fminf(mind[5], g1.y); mind[5] = m1;
                float m2 = fminf(mind[6], g1.z); mind[6] = m2;
                float m3 = fminf(mind[7], g1.w); mind[7] = m3;
                if (m0 > bv) { bv = m0; bj = j0 + 0; }
                if (m1 > bv) { bv = m1; bj = j0 + 1; }
                if (m2 > bv) { bv = m2; bj = j0 + 2; }
                if (m3 > bv) { bv = m3; bj = j0 + 3; }
            }
            // per-wave butterfly argmax, explicit lowest-index tie-break
#pragma unroll
            for (int off = 32; off > 0; off >>= 1) {
                float ov = __shfl_xor(bv, off);
                int oj = __shfl_xor(bj, off);
                if (ov > bv || (ov == bv && oj < bj)) { bv = ov; bj = oj; }
            }
            int lane = t & 63, w = t >> 6;
            if (lane == 0) red[w] = make_float2(bv, __int_as_float(bj));
            __syncthreads();
            if (t == 0) {
                float BV = red[0].x; int BJ = __float_as_int(red[0].y);
#pragma unroll
                for (int ww = 1; ww < 4; ww++) {
                    float v = red[ww].x; int j = __float_as_int(red[ww].y);
                    if (v > BV || (v == BV && j < BJ)) { BV = v; BJ = j; }
                }
                bc[0] = BJ;
                fps_idx[b * NCEN + s] = BJ;
            }
            __syncthreads();
            prev = bc[0];
        }
        return;
    }
    // ---------------- top-11 ----------------
    float* row = (float*)smem;
    float* rv = row + NPTS;
    int* ri = (int*)(rv + 256);
    int* picks = ri + 256;
    int rid = blockIdx.x - BATCH;
    const float* Dr = D + (size_t)rid * NPTS;
    int t = threadIdx.x;
    float4* rp = (float4*)row;
    rp[t] = ((const float4*)Dr)[t];
    rp[t + 256] = ((const float4*)Dr)[t + 256];
    __syncthreads();
    for (int it = 0; it < NTOP; it++) {
        float bv = row[t];
        int bi = t;
#pragma unroll
        for (int k = 1; k < 8; k++) {
            int j = t + (k << 8);
            float v = row[j];
            if (v < bv) { bv = v; bi = j; }
        }
        rv[t] = bv; ri[t] = bi;
        __syncthreads();
        for (int off = 128; off > 0; off >>= 1) {
            if (t < off) {
                float ovv = rv[t + off]; int oi = ri[t + off];
                if (ovv < rv[t] || (ovv == rv[t] && oi < ri[t])) { rv[t] = ovv; ri[t] = oi; }
            }
            __syncthreads();
        }
        if (t == 0) { picks[it] = ri[0]; row[ri[0]] = INFINITY; }
        __syncthreads();
    }
    if (t < NW) {
        unsigned w = 0;
#pragma unroll
        for (int p = 0; p < NTOP; p++) {
            int j = picks[p];
            if ((j >> 5) == t) w |= 1u << (j & 31);
        }
        adj[(size_t)rid * NW + t] = w;
    }
}

// ---------------------------------------------------------------- gather indices
__global__ void make_gather(const int* __restrict__ fps_idx, int* __restrict__ gatherC) {
    int r = blockIdx.x * 256 + threadIdx.x;
    if (r >= BATCH * NCEN) return;
    int b = r >> 9, s = r & 511;
    gatherC[r] = b * NPTS + fps_idx[b * NCEN + s];
}

// ---------------------------------------------------------------- 64x64 fp32 GEMM tile (smem arena)
template <int KSIZE, bool RELU>
__device__ __forceinline__ void gemm_tile64(char* smem,
                                            const float* __restrict__ A, int lda,
                                            const int* __restrict__ gather,
                                            const float* __restrict__ W, int ldw,
                                            const float* __restrict__ bias,
                                            float* __restrict__ Out, int ldo) {
    float (*As)[68] = (float(*)[68])smem;
    float (*Ws)[68] = (float(*)[68])(smem + 32 * 68 * 4);
    int t = threadIdx.x;
    int tx = t & 15, ty = t >> 4;
    int lr = t >> 3, lc = (t & 7) * 4;
    const float* ar0 = A + (size_t)(gather ? gather[lr] : lr) * lda;
    const float* ar1 = A + (size_t)(gather ? gather[lr + 32] : lr + 32) * lda;
    float acc[4][4] = {};
    for (int kc = 0; kc < KSIZE; kc += 32) {
        float4 a0 = *(const float4*)(ar0 + kc + lc);
        float4 a1 = *(const float4*)(ar1 + kc + lc);
        float4 w0 = *(const float4*)(W + (size_t)(kc + lr) * ldw + lc);
        float4 w1 = *(const float4*)(W + (size_t)(kc + lr) * ldw + lc + 32);
        __syncthreads();
        As[lc + 0][lr] = a0.x; As[lc + 1][lr] = a0.y; As[lc + 2][lr] = a0.z; As[lc + 3][lr] = a0.w;
        As[lc + 0][lr + 32] = a1.x; As[lc + 1][lr + 32] = a1.y; As[lc + 2][lr + 32] = a1.z; As[lc + 3][lr + 32] = a1.w;
        *(float4*)&Ws[lr][lc] = w0;
        *(float4*)&Ws[lr][lc + 32] = w1;
        __syncthreads();
#pragma unroll
        for (int kk = 0; kk < 32; kk++) {
            float4 av = *(const float4*)&As[kk][ty * 4];
            float4 wv = *(const float4*)&Ws[kk][tx * 4];
            float a[4] = {av.x, av.y, av.z, av.w};
            float w[4] = {wv.x, wv.y, wv.z, wv.w};
#pragma unroll
            for (int i = 0; i < 4; i++)
#pragma unroll
                for (int j = 0; j < 4; j++) acc[i][j] += a[i] * w[j];
        }
    }
#pragma unroll
    for (int i = 0; i < 4; i++) {
        int r = ty * 4 + i;
        float4 o;
        o.x = acc[i][0] + bias[tx * 4 + 0];
        o.y = acc[i][1] + bias[tx * 4 + 1];
        o.z = acc[i][2] + bias[tx * 4 + 2];
        o.w = acc[i][3] + bias[tx * 4 + 3];
        if (RELU) {
            o.x = fmaxf(o.x, 0.f); o.y = fmaxf(o.y, 0.f);
            o.z = fmaxf(o.z, 0.f); o.w = fmaxf(o.w, 0.f);
        }
        *(float4*)(Out + (size_t)r * ldo + tx * 4) = o;
    }
}

// ---------------------------------------------------------------- fused mid: reach+top32 (blocks 0..4095) + qproj (blocks 4096..4991)
__global__ __launch_bounds__(256) void fused_mid_kernel(const unsigned int* __restrict__ adj,
                                                        const float* __restrict__ D,
                                                        const int* __restrict__ fps_idx,
                                                        int* __restrict__ idx_sel,
                                                        Ptr7 feats,
                                                        const float* __restrict__ awq,
                                                        const float* __restrict__ abq,
                                                        const int* __restrict__ gatherC,
                                                        float* __restrict__ qtab) {
    __shared__ __align__(16) char smem[SMEM_MID];
    if (blockIdx.x >= NCEN * BATCH) {
        int id = blockIdx.x - NCEN * BATCH;    // 0..895
        int rt = id & 63;
        int ct = (id >> 6) & 1;
        int v = id >> 7;
        gemm_tile64<CH, false>(smem, feats.p[v], CH, gatherC + rt * 64,
                               awq + (size_t)v * CH * CH + ct * 64, CH,
                               abq + v * CH + ct * 64,
                               qtab + ((size_t)v * (BATCH * NCEN) + rt * 64) * CH + ct * 64, CH);
        return;
    }
    unsigned* adjw = (unsigned*)smem;
    unsigned* R1 = adjw + NW;
    unsigned* R2 = R1 + NW;
    int* cnt = (int*)(R2 + NW);
    int* lst = (int*)(smem + 1024);
    float* dst = (float*)(smem + 1024 + 8192);
    int* sel = (int*)(smem + 1024 + 16384);
    int s = blockIdx.x & (NCEN - 1), b = blockIdx.x >> 9, t = threadIdx.x;
    int i = fps_idx[b * NCEN + s];
    const unsigned* arow = adj + ((size_t)(b * NPTS + i)) * NW;
    if (t < NW) { adjw[t] = arow[t]; R1[t] = arow[t]; }
    if (t == 0) cnt[0] = 0;
    __syncthreads();
    if (t < NW) {
        unsigned w = adjw[t];
        while (w) { int bb = __ffs(w) - 1; w &= w - 1; int p = atomicAdd(cnt, 1); lst[p] = t * 32 + bb; }
    }
    __syncthreads();
    int n1 = cnt[0];
    {
        int g = t >> 6, lane = t & 63;
        for (int p = g; p < n1; p += 4) {
            unsigned aw = adj[((size_t)(b * NPTS + lst[p])) * NW + lane];
            atomicOr(&R1[lane], aw);
        }
    }
    __syncthreads();
    if (t == 0) cnt[0] = 0;
    __syncthreads();
    if (t < NW) {
        unsigned w = R1[t];
        while (w) { int bb = __ffs(w) - 1; w &= w - 1; int p = atomicAdd(cnt, 1); lst[p] = t * 32 + bb; }
        R2[t] = adjw[t];
    }
    __syncthreads();
    int n2 = cnt[0];
    {
        int g = t >> 6, lane = t & 63;
        for (int p = g; p < n2; p += 4) {
            unsigned aw = adj[((size_t)(b * NPTS + lst[p])) * NW + lane];
            atomicOr(&R2[lane], aw);
        }
    }
    __syncthreads();
    if (t == 0) cnt[0] = 0;
    __syncthreads();
    const float* Dr = D + (size_t)(b * NPTS + i) * NPTS;
    if (t < NW) {
        unsigned w = R2[t];
        while (w) {
            int bb = __ffs(w) - 1; w &= w - 1;
            int j = t * 32 + bb;
            int p = atomicAdd(cnt, 1);
            lst[p] = j; dst[p] = Dr[j];
        }
    }
    __syncthreads();
    if (t >= 64) return;               // selection on wave 0 only
    int L = cnt[0];
    int nsel = L < NNEI ? L : NNEI;
    int lane = t;
    for (int r = 0; r < nsel; r++) {
        float bv = INFINITY; int bj = 0x7fffffff, bp = -1;
        for (int p = lane; p < L; p += 64) {
            float v = dst[p]; int j = lst[p];
            if (v < bv || (v == bv && j < bj)) { bv = v; bj = j; bp = p; }
        }
#pragma unroll
        for (int off = 32; off > 0; off >>= 1) {
            float ov = __shfl_xor(bv, off);
            int oj = __shfl_xor(bj, off);
            int op = __shfl_xor(bp, off);
            if (ov < bv || (ov == bv && oj < bj)) { bv = ov; bj = oj; bp = op; }
        }
        if (lane == 0) { sel[r] = bj; dst[bp] = INFINITY; }
    }
    if (lane == 0 && nsel < NNEI) {
        int r = nsel;
        for (int j = 0; j < NPTS && r < NNEI; j++)
            if (!((R2[j >> 5] >> (j & 31)) & 1)) sel[r++] = j;
    }
    if (lane < NNEI) idx_sel[((size_t)(b * NCEN + s)) * NNEI + lane] = sel[lane];
}

// ---------------------------------------------------------------- GEMM wrappers
__global__ __launch_bounds__(256) void kvproj_kernel(Ptr7 feats, const float* __restrict__ awk,
                                                     const float* __restrict__ abk,
                                                     const float* __restrict__ awv,
                                                     const float* __restrict__ abv,
                                                     float* __restrict__ ktab,
                                                     float* __restrict__ vtab) {
    __shared__ __align__(16) char smem[SMEM_BYTES];
    int v = blockIdx.z, ct = blockIdx.y, rt = blockIdx.x;
    bool isv = ct >= 2;
    int c2 = ct & 1;
    const float* A = feats.p[v] + (size_t)rt * 64 * CH;
    const float* W = (isv ? awv : awk) + (size_t)v * CH * CH + c2 * 64;
    const float* bias = (isv ? abv : abk) + v * CH + c2 * 64;
    float* Out = (isv ? vtab : ktab) + (size_t)v * (BATCH * NPTS) * CH + (size_t)rt * 64 * CH + c2 * 64;
    gemm_tile64<CH, false>(smem, A, CH, nullptr, W, CH, bias, Out, CH);
}

__global__ __launch_bounds__(256) void mlp1_kernel(const float* __restrict__ otab,
                                                   const float* __restrict__ mw1,
                                                   const float* __restrict__ mb1,
                                                   float* __restrict__ htab) {
    __shared__ __align__(16) char smem[SMEM_BYTES];
    int v = blockIdx.z, ct = blockIdx.y, rt = blockIdx.x;
    gemm_tile64<CH, true>(smem, otab + ((size_t)v * (BATCH * NCEN) + rt * 64) * CH, CH, nullptr,
                          mw1 + (size_t)v * CH * CHO + ct * 64, CHO,
                          mb1 + v * CHO + ct * 64,
                          htab + ((size_t)v * (BATCH * NCEN) + rt * 64) * CHO + ct * 64, CHO);
}

__global__ __launch_bounds__(256) void mlp2_kernel(const float* __restrict__ htab,
                                                   const float* __restrict__ mw2,
                                                   const float* __restrict__ mb2,
                                                   float* __restrict__ out) {
    __shared__ __align__(16) char smem[SMEM_BYTES];
    int v = blockIdx.z, ct = blockIdx.y, rt = blockIdx.x;
    gemm_tile64<CHO, true>(smem, htab + ((size_t)v * (BATCH * NCEN) + rt * 64) * CHO, CHO, nullptr,
                           mw2 + (size_t)v * CHO * CHO + ct * 64, CHO,
                           mb2 + v * CHO + ct * 64,
                           out + ((size_t)v * (BATCH * NCEN) + rt * 64) * CHO + ct * 64, CHO);
}

// ---------------------------------------------------------------- attention
__global__ __launch_bounds__(256) void attn_kernel(const float* __restrict__ qtab,
                                                   const float* __restrict__ ktab,
                                                   const float* __restrict__ vtab,
                                                   const int* __restrict__ idx_sel,
                                                   float* __restrict__ otab) {
    __shared__ float q_s[4][CH];
    __shared__ float attn_s[4][NNEI];
    __shared__ int jj_s[4][NNEI];
    int v = blockIdx.y;
    int t = threadIdx.x, w = t >> 6, lane = t & 63;
    int cg = blockIdx.x * 4 + w;
    int b = cg >> 9, s = cg & 511;
    const float* qr = qtab + ((size_t)v * (BATCH * NCEN) + cg) * CH;
    *(float2*)&q_s[w][lane * 2] = *(const float2*)(qr + lane * 2);
    if (lane < NNEI) jj_s[w][lane] = idx_sel[((size_t)(b * NCEN + s)) * NNEI + lane];
    __syncthreads();
    if (lane < NNEI) {
        int j = jj_s[w][lane];
        const float* kr = ktab + ((size_t)v * (BATCH * NPTS) + b * NPTS + j) * CH;
        float acc = 0.f;
#pragma unroll
        for (int c4 = 0; c4 < CH / 4; c4++) {
            float4 qv = *(const float4*)&q_s[w][c4 * 4];
            float4 kv = *(const float4*)(kr + c4 * 4);
            acc += qv.x * kv.x + qv.y * kv.y + qv.z * kv.z + qv.w * kv.w;
        }
        float sc = acc * 0.08838834764831845f;  // 1/sqrt(128)
        float m = sc;
#pragma unroll
        for (int off = 16; off > 0; off >>= 1) m = fmaxf(m, __shfl_xor(m, off, 32));
        float e = expf(sc - m);
        float sum = e;
#pragma unroll
        for (int off = 16; off > 0; off >>= 1) sum += __shfl_xor(sum, off, 32);
        attn_s[w][lane] = e / sum;
    }
    __syncthreads();
    float2 o = {0.f, 0.f};
    const float* vbase = vtab + ((size_t)v * (BATCH * NPTS) + b * NPTS) * CH;
    for (int tt = 0; tt < NNEI; tt++) {
        int j = jj_s[w][tt];
        float a = attn_s[w][tt];
        float2 vv = *(const float2*)(vbase + (size_t)j * CH + lane * 2);
        o.x += a * vv.x;
        o.y += a * vv.y;
    }
    *(float2*)(otab + ((size_t)v * (BATCH * NCEN) + cg) * CH + lane * 2) = o;
}

// ---------------------------------------------------------------- launch
extern "C" void kernel_launch(void* const* d_in, const int* in_sizes, int n_in,
                              void* d_out, int out_size, void* d_ws, size_t ws_size,
                              hipStream_t stream) {
    (void)in_sizes; (void)n_in; (void)out_size;
    Ptr7 feats;
    for (int i = 0; i < 7; i++) feats.p[i] = (const float*)d_in[i];
    const float* awq = (const float*)d_in[7];
    const float* abq = (const float*)d_in[8];
    const float* awk = (const float*)d_in[9];
    const float* abk = (const float*)d_in[10];
    const float* awv = (const float*)d_in[11];
    const float* abv = (const float*)d_in[12];
    const float* mw1 = (const float*)d_in[13];
    const float* mb1 = (const float*)d_in[14];
    const float* mw2 = (const float*)d_in[15];
    const float* mb2 = (const float*)d_in[16];
    const float* xyz = feats.p[0];

    char* ws = (char*)d_ws;
    size_t SZ_D = (size_t)BATCH * NPTS * NPTS * 4;       // 134 MB
    float* D = (float*)ws;
    float* ktab = (float*)ws;                            // overlays D (dead after reach)
    float* vtab = (float*)(ws + (size_t)7 * BATCH * NPTS * CH * 4);
    size_t off = SZ_D;
    float* xx = (float*)(ws + off); off += (size_t)BATCH * NPTS * 4;
    unsigned* adjb = (unsigned*)(ws + off); off += (size_t)BATCH * NPTS * NW * 4;
    int* fpsidx = (int*)(ws + off); off += (size_t)BATCH * NCEN * 4;
    int* idxsel = (int*)(ws + off); off += (size_t)BATCH * NCEN * NNEI * 4;
    int* gatherC = (int*)(ws + off); off += (size_t)BATCH * NCEN * 4;
    float* qtab = (float*)(ws + off); off += (size_t)7 * BATCH * NCEN * CH * 4;
    float* otab = (float*)(ws + off); off += (size_t)7 * BATCH * NCEN * CH * 4;
    float* htab = (float*)(ws + off); off += (size_t)7 * BATCH * NCEN * CHO * 4;
    if (ws_size < off) return;

    xx_kernel<<<dim3((BATCH * NPTS + 255) / 256), dim3(256), 0, stream>>>(xyz, xx);
    dmat_kernel<<<dim3(NPTS / 64, NPTS / 64, BATCH), dim3(256), 0, stream>>>(xyz, xx, D);
    fused_front_kernel<<<dim3(BATCH + BATCH * NPTS), dim3(256), 0, stream>>>(D, adjb, fpsidx);
    make_gather<<<dim3((BATCH * NCEN + 255) / 256), dim3(256), 0, stream>>>(fpsidx, gatherC);
    fused_mid_kernel<<<dim3(NCEN * BATCH + 2 * 7 * (BATCH * NCEN / 64)), dim3(256), 0, stream>>>(
        adjb, D, fpsidx, idxsel, feats, awq, abq, gatherC, qtab);
    // D dead: ktab/vtab overlay it
    kvproj_kernel<<<dim3(BATCH * NPTS / 64, 4, 7), dim3(256), 0, stream>>>(feats, awk, abk, awv, abv, ktab, vtab);
    attn_kernel<<<dim3(BATCH * NCEN / 4, 7), dim3(256), 0, stream>>>(qtab, ktab, vtab, idxsel, otab);
    mlp1_kernel<<<dim3(BATCH * NCEN / 64, 4, 7), dim3(256), 0, stream>>>(otab, mw1, mb1, htab);
    mlp2_kernel<<<dim3(BATCH * NCEN / 64, 4, 7), dim3(256), 0, stream>>>(htab, mw2, mb2, (float*)d_out);
}

// Round 22
// 1086.787 us; speedup vs baseline: 1.0728x; 1.0728x over previous
//
#include <hip/hip_runtime.h>
#include <hip/hip_bf16.h>
#include <math.h>

// Problem constants
constexpr int BATCH = 8;
constexpr int NPTS  = 2048;
constexpr int CH    = 128;
constexpr int CHO   = 256;
constexpr int NCEN  = 512;
constexpr int NNEI  = 32;   // n_near
constexpr int NTOP  = 11;   // n_stepk + 1
constexpr int NW    = 64;   // bitset words per row (2048/32)
constexpr int SMEM_BYTES = 17408;   // gemm/top11/fps arena
constexpr int SMEM_MID   = 20608;   // reach arena (superset of gemm arena)

struct Ptr7 { const float* p[7]; };

// ---------------------------------------------------------------- xx = sum(x^2)
__global__ __launch_bounds__(256) void xx_kernel(const float* __restrict__ x,
                                                 float* __restrict__ xx) {
    int p = blockIdx.x * 256 + threadIdx.x;
    if (p >= BATCH * NPTS) return;
    const float4* xr = (const float4*)(x + (size_t)p * CH);
    float s = 0.f;
#pragma unroll
    for (int i = 0; i < CH / 4; i++) {
        float4 v = xr[i];
        s += v.x * v.x + v.y * v.y + v.z * v.z + v.w * v.w;
    }
    xx[p] = s;
}

// ---------------------------------------------------------------- D (symmetric: jt>=it tiles, mirrored; bitwise-faithful)
__global__ __launch_bounds__(256) void dmat_kernel(const float* __restrict__ x,
                                                   const float* __restrict__ xx,
                                                   float* __restrict__ D) {
    __shared__ __align__(16) char smem[SMEM_BYTES];
    int it = blockIdx.y, jt = blockIdx.x;
    if (jt < it) return;
    float (*As)[68] = (float(*)[68])smem;
    float (*Bs)[68] = (float(*)[68])(smem + 32 * 68 * 4);
    int bz = blockIdx.z;
    int i0 = it * 64, j0 = jt * 64;
    const float* X = x + (size_t)bz * NPTS * CH;
    int t = threadIdx.x, tx = t & 15, ty = t >> 4;
    int lr = t >> 3, lc = (t & 7) * 4;
    const float* ai0 = X + (size_t)(i0 + lr) * CH;
    const float* ai1 = X + (size_t)(i0 + lr + 32) * CH;
    const float* bj0 = X + (size_t)(j0 + lr) * CH;
    const float* bj1 = X + (size_t)(j0 + lr + 32) * CH;
    float acc[4][4] = {};
    for (int kc = 0; kc < CH; kc += 32) {
        float4 a0 = *(const float4*)(ai0 + kc + lc);
        float4 a1 = *(const float4*)(ai1 + kc + lc);
        float4 b0 = *(const float4*)(bj0 + kc + lc);
        float4 b1 = *(const float4*)(bj1 + kc + lc);
        __syncthreads();
        As[lc + 0][lr] = a0.x; As[lc + 1][lr] = a0.y; As[lc + 2][lr] = a0.z; As[lc + 3][lr] = a0.w;
        As[lc + 0][lr + 32] = a1.x; As[lc + 1][lr + 32] = a1.y; As[lc + 2][lr + 32] = a1.z; As[lc + 3][lr + 32] = a1.w;
        Bs[lc + 0][lr] = b0.x; Bs[lc + 1][lr] = b0.y; Bs[lc + 2][lr] = b0.z; Bs[lc + 3][lr] = b0.w;
        Bs[lc + 0][lr + 32] = b1.x; Bs[lc + 1][lr + 32] = b1.y; Bs[lc + 2][lr + 32] = b1.z; Bs[lc + 3][lr + 32] = b1.w;
        __syncthreads();
#pragma unroll
        for (int kk = 0; kk < 32; kk++) {
            float4 av = *(const float4*)&As[kk][ty * 4];
            float4 bv = *(const float4*)&Bs[kk][tx * 4];
            float a[4] = {av.x, av.y, av.z, av.w};
            float b[4] = {bv.x, bv.y, bv.z, bv.w};
#pragma unroll
            for (int i = 0; i < 4; i++)
#pragma unroll
                for (int j = 0; j < 4; j++) acc[i][j] += a[i] * b[j];
        }
    }
    const float* xxb = xx + bz * NPTS;
    float xi[4], xj[4];
#pragma unroll
    for (int i = 0; i < 4; i++) xi[i] = xxb[i0 + ty * 4 + i];
#pragma unroll
    for (int j = 0; j < 4; j++) xj[j] = xxb[j0 + tx * 4 + j];
    float ov[4][4];
#pragma unroll
    for (int i = 0; i < 4; i++)
#pragma unroll
        for (int j = 0; j < 4; j++) ov[i][j] = xi[i] + xj[j] - 2.f * acc[i][j];
#pragma unroll
    for (int i = 0; i < 4; i++) {
        float4 o = {ov[i][0], ov[i][1], ov[i][2], ov[i][3]};
        *(float4*)(D + ((size_t)bz * NPTS + i0 + ty * 4 + i) * NPTS + j0 + tx * 4) = o;
    }
    if (jt > it) {
        __syncthreads();
        float (*T)[65] = (float(*)[65])smem;
#pragma unroll
        for (int i = 0; i < 4; i++)
#pragma unroll
            for (int j = 0; j < 4; j++) T[ty * 4 + i][tx * 4 + j] = ov[i][j];
        __syncthreads();
#pragma unroll
        for (int i = 0; i < 4; i++) {
            float4 o;
            o.x = T[tx * 4 + 0][ty * 4 + i];
            o.y = T[tx * 4 + 1][ty * 4 + i];
            o.z = T[tx * 4 + 2][ty * 4 + i];
            o.w = T[tx * 4 + 3][ty * 4 + i];
            *(float4*)(D + ((size_t)bz * NPTS + j0 + ty * 4 + i) * NPTS + i0 + tx * 4) = o;
        }
    }
}

// ---------------------------------------------------------------- 64x64 fp32 GEMM tile (smem arena)
template <int KSIZE, bool RELU>
__device__ __forceinline__ void gemm_tile64(char* smem,
                                            const float* __restrict__ A, int lda,
                                            const int* __restrict__ gather,
                                            const float* __restrict__ W, int ldw,
                                            const float* __restrict__ bias,
                                            float* __restrict__ Out, int ldo) {
    float (*As)[68] = (float(*)[68])smem;
    float (*Ws)[68] = (float(*)[68])(smem + 32 * 68 * 4);
    int t = threadIdx.x;
    int tx = t & 15, ty = t >> 4;
    int lr = t >> 3, lc = (t & 7) * 4;
    const float* ar0 = A + (size_t)(gather ? gather[lr] : lr) * lda;
    const float* ar1 = A + (size_t)(gather ? gather[lr + 32] : lr + 32) * lda;
    float acc[4][4] = {};
    for (int kc = 0; kc < KSIZE; kc += 32) {
        float4 a0 = *(const float4*)(ar0 + kc + lc);
        float4 a1 = *(const float4*)(ar1 + kc + lc);
        float4 w0 = *(const float4*)(W + (size_t)(kc + lr) * ldw + lc);
        float4 w1 = *(const float4*)(W + (size_t)(kc + lr) * ldw + lc + 32);
        __syncthreads();
        As[lc + 0][lr] = a0.x; As[lc + 1][lr] = a0.y; As[lc + 2][lr] = a0.z; As[lc + 3][lr] = a0.w;
        As[lc + 0][lr + 32] = a1.x; As[lc + 1][lr + 32] = a1.y; As[lc + 2][lr + 32] = a1.z; As[lc + 3][lr + 32] = a1.w;
        *(float4*)&Ws[lr][lc] = w0;
        *(float4*)&Ws[lr][lc + 32] = w1;
        __syncthreads();
#pragma unroll
        for (int kk = 0; kk < 32; kk++) {
            float4 av = *(const float4*)&As[kk][ty * 4];
            float4 wv = *(const float4*)&Ws[kk][tx * 4];
            float a[4] = {av.x, av.y, av.z, av.w};
            float w[4] = {wv.x, wv.y, wv.z, wv.w};
#pragma unroll
            for (int i = 0; i < 4; i++)
#pragma unroll
                for (int j = 0; j < 4; j++) acc[i][j] += a[i] * w[j];
        }
    }
#pragma unroll
    for (int i = 0; i < 4; i++) {
        int r = ty * 4 + i;
        float4 o;
        o.x = acc[i][0] + bias[tx * 4 + 0];
        o.y = acc[i][1] + bias[tx * 4 + 1];
        o.z = acc[i][2] + bias[tx * 4 + 2];
        o.w = acc[i][3] + bias[tx * 4 + 3];
        if (RELU) {
            o.x = fmaxf(o.x, 0.f); o.y = fmaxf(o.y, 0.f);
            o.z = fmaxf(o.z, 0.f); o.w = fmaxf(o.w, 0.f);
        }
        *(float4*)(Out + (size_t)r * ldo + tx * 4) = o;
    }
}

// ---------------------------------------------------------------- fused front: fps (blocks 0..7) + top-11 + optional k-proj tiles
// fps: round-20 1-wave LDS-mind version (best measured: 566 us).
__global__ __launch_bounds__(256) void fused_front_kernel(const float* __restrict__ D,
                                                          unsigned int* __restrict__ adj,
                                                          int* __restrict__ fps_idx,
                                                          Ptr7 feats,
                                                          const float* __restrict__ awk,
                                                          const float* __restrict__ abk,
                                                          float* __restrict__ ktab) {
    __shared__ __align__(16) char smem[SMEM_BYTES];
    if (blockIdx.x < BATCH) {
        int lane = threadIdx.x;
        if (lane >= 64) return;                    // single wave; LDS ops in-order within wave
        int b = blockIdx.x;
        float4* mp = (float4*)smem;                // 512 float4 = 2048 mind values
        float4 inf4 = {INFINITY, INFINITY, INFINITY, INFINITY};
#pragma unroll
        for (int k = 0; k < 8; k++) mp[lane + 64 * k] = inf4;
        int prev = 0;
        if (lane == 0) fps_idx[b * NCEN] = 0;
        const float* Db = D + (size_t)b * NPTS * NPTS;
        for (int s = 1; s < NCEN; s++) {
            const float4* rowp = (const float4*)(Db + (size_t)prev * NPTS);
            float4 g0 = rowp[lane + 0 * 64];
            float4 g1 = rowp[lane + 1 * 64];
            float4 g2 = rowp[lane + 2 * 64];
            float4 g3 = rowp[lane + 3 * 64];
            float4 g4 = rowp[lane + 4 * 64];
            float4 g5 = rowp[lane + 5 * 64];
            float4 g6 = rowp[lane + 6 * 64];
            float4 g7 = rowp[lane + 7 * 64];
            float4 gg[8] = {g0, g1, g2, g3, g4, g5, g6, g7};
            float bv = -INFINITY; int bj = NPTS;
#pragma unroll
            for (int k = 0; k < 8; k++) {
                int li = lane + 64 * k;
                float4 m = mp[li];
                m.x = fminf(m.x, gg[k].x);
                m.y = fminf(m.y, gg[k].y);
                m.z = fminf(m.z, gg[k].z);
                m.w = fminf(m.w, gg[k].w);
                mp[li] = m;
                int j0 = 4 * li;
                // ascending j -> strict > keeps lowest index on ties
                if (m.x > bv) { bv = m.x; bj = j0 + 0; }
                if (m.y > bv) { bv = m.y; bj = j0 + 1; }
                if (m.z > bv) { bv = m.z; bj = j0 + 2; }
                if (m.w > bv) { bv = m.w; bj = j0 + 3; }
            }
#pragma unroll
            for (int off = 32; off > 0; off >>= 1) {
                float ov = __shfl_xor(bv, off);
                int oj = __shfl_xor(bj, off);
                if (ov > bv || (ov == bv && oj < bj)) { bv = ov; bj = oj; }
            }
            if (lane == 0) fps_idx[b * NCEN + s] = bj;
            prev = bj;   // all lanes agree
        }
        return;
    }
    if (blockIdx.x < BATCH + BATCH * NPTS) {
        // ---------------- top-11 ----------------
        float* row = (float*)smem;
        float* rv = row + NPTS;
        int* ri = (int*)(rv + 256);
        int* picks = ri + 256;
        int rid = blockIdx.x - BATCH;
        const float* Dr = D + (size_t)rid * NPTS;
        int t = threadIdx.x;
        float4* rp = (float4*)row;
        rp[t] = ((const float4*)Dr)[t];
        rp[t + 256] = ((const float4*)Dr)[t + 256];
        __syncthreads();
        for (int it = 0; it < NTOP; it++) {
            float bv = row[t];
            int bi = t;
#pragma unroll
            for (int k = 1; k < 8; k++) {
                int j = t + (k << 8);
                float v = row[j];
                if (v < bv) { bv = v; bi = j; }
            }
            rv[t] = bv; ri[t] = bi;
            __syncthreads();
            for (int off = 128; off > 0; off >>= 1) {
                if (t < off) {
                    float ovv = rv[t + off]; int oi = ri[t + off];
                    if (ovv < rv[t] || (ovv == rv[t] && oi < ri[t])) { rv[t] = ovv; ri[t] = oi; }
                }
                __syncthreads();
            }
            if (t == 0) { picks[it] = ri[0]; row[ri[0]] = INFINITY; }
            __syncthreads();
        }
        if (t < NW) {
            unsigned w = 0;
#pragma unroll
            for (int p = 0; p < NTOP; p++) {
                int j = picks[p];
                if ((j >> 5) == t) w |= 1u << (j & 31);
            }
            adj[(size_t)rid * NW + t] = w;
        }
        return;
    }
    // ---------------- k-proj tiles (only when ktab is a separate buffer) ----------------
    {
        int id = blockIdx.x - BATCH - BATCH * NPTS;   // 0..3583
        int rt = id & 255;                            // 256 row tiles
        int c2 = (id >> 8) & 1;                       // 2 col halves
        int v = id >> 9;                              // 7 branches
        const float* A = feats.p[v] + (size_t)rt * 64 * CH;
        const float* W = awk + (size_t)v * CH * CH + c2 * 64;
        const float* bias = abk + v * CH + c2 * 64;
        float* Out = ktab + (size_t)v * (BATCH * NPTS) * CH + (size_t)rt * 64 * CH + c2 * 64;
        gemm_tile64<CH, false>(smem, A, CH, nullptr, W, CH, bias, Out, CH);
    }
}

// ---------------------------------------------------------------- gather indices
__global__ void make_gather(const int* __restrict__ fps_idx, int* __restrict__ gatherC) {
    int r = blockIdx.x * 256 + threadIdx.x;
    if (r >= BATCH * NCEN) return;
    int b = r >> 9, s = r & 511;
    gatherC[r] = b * NPTS + fps_idx[b * NCEN + s];
}

// ---------------------------------------------------------------- fused mid: reach+top32 (blocks 0..4095) + qproj (blocks 4096..4991)
__global__ __launch_bounds__(256) void fused_mid_kernel(const unsigned int* __restrict__ adj,
                                                        const float* __restrict__ D,
                                                        const int* __restrict__ fps_idx,
                                                        int* __restrict__ idx_sel,
                                                        Ptr7 feats,
                                                        const float* __restrict__ awq,
                                                        const float* __restrict__ abq,
                                                        const int* __restrict__ gatherC,
                                                        float* __restrict__ qtab) {
    __shared__ __align__(16) char smem[SMEM_MID];
    if (blockIdx.x >= NCEN * BATCH) {
        int id = blockIdx.x - NCEN * BATCH;    // 0..895
        int rt = id & 63;
        int ct = (id >> 6) & 1;
        int v = id >> 7;
        gemm_tile64<CH, false>(smem, feats.p[v], CH, gatherC + rt * 64,
                               awq + (size_t)v * CH * CH + ct * 64, CH,
                               abq + v * CH + ct * 64,
                               qtab + ((size_t)v * (BATCH * NCEN) + rt * 64) * CH + ct * 64, CH);
        return;
    }
    unsigned* adjw = (unsigned*)smem;
    unsigned* R1 = adjw + NW;
    unsigned* R2 = R1 + NW;
    int* cnt = (int*)(R2 + NW);
    int* lst = (int*)(smem + 1024);
    float* dst = (float*)(smem + 1024 + 8192);
    int* sel = (int*)(smem + 1024 + 16384);
    int s = blockIdx.x & (NCEN - 1), b = blockIdx.x >> 9, t = threadIdx.x;
    int i = fps_idx[b * NCEN + s];
    const unsigned* arow = adj + ((size_t)(b * NPTS + i)) * NW;
    if (t < NW) { adjw[t] = arow[t]; R1[t] = arow[t]; }
    if (t == 0) cnt[0] = 0;
    __syncthreads();
    if (t < NW) {
        unsigned w = adjw[t];
        while (w) { int bb = __ffs(w) - 1; w &= w - 1; int p = atomicAdd(cnt, 1); lst[p] = t * 32 + bb; }
    }
    __syncthreads();
    int n1 = cnt[0];
    {
        int g = t >> 6, lane = t & 63;
        for (int p = g; p < n1; p += 4) {
            unsigned aw = adj[((size_t)(b * NPTS + lst[p])) * NW + lane];
            atomicOr(&R1[lane], aw);
        }
    }
    __syncthreads();
    if (t == 0) cnt[0] = 0;
    __syncthreads();
    if (t < NW) {
        unsigned w = R1[t];
        while (w) { int bb = __ffs(w) - 1; w &= w - 1; int p = atomicAdd(cnt, 1); lst[p] = t * 32 + bb; }
        R2[t] = adjw[t];
    }
    __syncthreads();
    int n2 = cnt[0];
    {
        int g = t >> 6, lane = t & 63;
        for (int p = g; p < n2; p += 4) {
            unsigned aw = adj[((size_t)(b * NPTS + lst[p])) * NW + lane];
            atomicOr(&R2[lane], aw);
        }
    }
    __syncthreads();
    if (t == 0) cnt[0] = 0;
    __syncthreads();
    const float* Dr = D + (size_t)(b * NPTS + i) * NPTS;
    if (t < NW) {
        unsigned w = R2[t];
        while (w) {
            int bb = __ffs(w) - 1; w &= w - 1;
            int j = t * 32 + bb;
            int p = atomicAdd(cnt, 1);
            lst[p] = j; dst[p] = Dr[j];
        }
    }
    __syncthreads();
    if (t >= 64) return;               // selection on wave 0 only
    int L = cnt[0];
    int nsel = L < NNEI ? L : NNEI;
    int lane = t;
    for (int r = 0; r < nsel; r++) {
        float bv = INFINITY; int bj = 0x7fffffff, bp = -1;
        for (int p = lane; p < L; p += 64) {
            float v = dst[p]; int j = lst[p];
            if (v < bv || (v == bv && j < bj)) { bv = v; bj = j; bp = p; }
        }
#pragma unroll
        for (int off = 32; off > 0; off >>= 1) {
            float ov = __shfl_xor(bv, off);
            int oj = __shfl_xor(bj, off);
            int op = __shfl_xor(bp, off);
            if (ov < bv || (ov == bv && oj < bj)) { bv = ov; bj = oj; bp = op; }
        }
        if (lane == 0) { sel[r] = bj; dst[bp] = INFINITY; }
    }
    if (lane == 0 && nsel < NNEI) {
        int r = nsel;
        for (int j = 0; j < NPTS && r < NNEI; j++)
            if (!((R2[j >> 5] >> (j & 31)) & 1)) sel[r++] = j;
    }
    if (lane < NNEI) idx_sel[((size_t)(b * NCEN + s)) * NNEI + lane] = sel[lane];
}

// ---------------------------------------------------------------- GEMM wrappers
__global__ __launch_bounds__(256) void kvproj_kernel(Ptr7 feats, const float* __restrict__ awk,
                                                     const float* __restrict__ abk,
                                                     const float* __restrict__ awv,
                                                     const float* __restrict__ abv,
                                                     float* __restrict__ ktab,
                                                     float* __restrict__ vtab) {
    __shared__ __align__(16) char smem[SMEM_BYTES];
    int v = blockIdx.z, ct = blockIdx.y, rt = blockIdx.x;
    bool isv = ct >= 2;
    int c2 = ct & 1;
    const float* A = feats.p[v] + (size_t)rt * 64 * CH;
    const float* W = (isv ? awv : awk) + (size_t)v * CH * CH + c2 * 64;
    const float* bias = (isv ? abv : abk) + v * CH + c2 * 64;
    float* Out = (isv ? vtab : ktab) + (size_t)v * (BATCH * NPTS) * CH + (size_t)rt * 64 * CH + c2 * 64;
    gemm_tile64<CH, false>(smem, A, CH, nullptr, W, CH, bias, Out, CH);
}

__global__ __launch_bounds__(256) void vproj_kernel(Ptr7 feats,
                                                    const float* __restrict__ awv,
                                                    const float* __restrict__ abv,
                                                    float* __restrict__ vtab) {
    __shared__ __align__(16) char smem[SMEM_BYTES];
    int v = blockIdx.z, c2 = blockIdx.y, rt = blockIdx.x;
    const float* A = feats.p[v] + (size_t)rt * 64 * CH;
    const float* W = awv + (size_t)v * CH * CH + c2 * 64;
    const float* bias = abv + v * CH + c2 * 64;
    float* Out = vtab + (size_t)v * (BATCH * NPTS) * CH + (size_t)rt * 64 * CH + c2 * 64;
    gemm_tile64<CH, false>(smem, A, CH, nullptr, W, CH, bias, Out, CH);
}

__global__ __launch_bounds__(256) void mlp1_kernel(const float* __restrict__ otab,
                                                   const float* __restrict__ mw1,
                                                   const float* __restrict__ mb1,
                                                   float* __restrict__ htab) {
    __shared__ __align__(16) char smem[SMEM_BYTES];
    int v = blockIdx.z, ct = blockIdx.y, rt = blockIdx.x;
    gemm_tile64<CH, true>(smem, otab + ((size_t)v * (BATCH * NCEN) + rt * 64) * CH, CH, nullptr,
                          mw1 + (size_t)v * CH * CHO + ct * 64, CHO,
                          mb1 + v * CHO + ct * 64,
                          htab + ((size_t)v * (BATCH * NCEN) + rt * 64) * CHO + ct * 64, CHO);
}

__global__ __launch_bounds__(256) void mlp2_kernel(const float* __restrict__ htab,
                                                   const float* __restrict__ mw2,
                                                   const float* __restrict__ mb2,
                                                   float* __restrict__ out) {
    __shared__ __align__(16) char smem[SMEM_BYTES];
    int v = blockIdx.z, ct = blockIdx.y, rt = blockIdx.x;
    gemm_tile64<CHO, true>(smem, htab + ((size_t)v * (BATCH * NCEN) + rt * 64) * CHO, CHO, nullptr,
                           mw2 + (size_t)v * CHO * CHO + ct * 64, CHO,
                           mb2 + v * CHO + ct * 64,
                           out + ((size_t)v * (BATCH * NCEN) + rt * 64) * CHO + ct * 64, CHO);
}

// ---------------------------------------------------------------- attention
__global__ __launch_bounds__(256) void attn_kernel(const float* __restrict__ qtab,
                                                   const float* __restrict__ ktab,
                                                   const float* __restrict__ vtab,
                                                   const int* __restrict__ idx_sel,
                                                   float* __restrict__ otab) {
    __shared__ float q_s[4][CH];
    __shared__ float attn_s[4][NNEI];
    __shared__ int jj_s[4][NNEI];
    int v = blockIdx.y;
    int t = threadIdx.x, w = t >> 6, lane = t & 63;
    int cg = blockIdx.x * 4 + w;
    int b = cg >> 9, s = cg & 511;
    const float* qr = qtab + ((size_t)v * (BATCH * NCEN) + cg) * CH;
    *(float2*)&q_s[w][lane * 2] = *(const float2*)(qr + lane * 2);
    if (lane < NNEI) jj_s[w][lane] = idx_sel[((size_t)(b * NCEN + s)) * NNEI + lane];
    __syncthreads();
    if (lane < NNEI) {
        int j = jj_s[w][lane];
        const float* kr = ktab + ((size_t)v * (BATCH * NPTS) + b * NPTS + j) * CH;
        float acc = 0.f;
#pragma unroll
        for (int c4 = 0; c4 < CH / 4; c4++) {
            float4 qv = *(const float4*)&q_s[w][c4 * 4];
            float4 kv = *(const float4*)(kr + c4 * 4);
            acc += qv.x * kv.x + qv.y * kv.y + qv.z * kv.z + qv.w * kv.w;
        }
        float sc = acc * 0.08838834764831845f;  // 1/sqrt(128)
        float m = sc;
#pragma unroll
        for (int off = 16; off > 0; off >>= 1) m = fmaxf(m, __shfl_xor(m, off, 32));
        float e = expf(sc - m);
        float sum = e;
#pragma unroll
        for (int off = 16; off > 0; off >>= 1) sum += __shfl_xor(sum, off, 32);
        attn_s[w][lane] = e / sum;
    }
    __syncthreads();
    float2 o = {0.f, 0.f};
    const float* vbase = vtab + ((size_t)v * (BATCH * NPTS) + b * NPTS) * CH;
    for (int tt = 0; tt < NNEI; tt++) {
        int j = jj_s[w][tt];
        float a = attn_s[w][tt];
        float2 vv = *(const float2*)(vbase + (size_t)j * CH + lane * 2);
        o.x += a * vv.x;
        o.y += a * vv.y;
    }
    *(float2*)(otab + ((size_t)v * (BATCH * NCEN) + cg) * CH + lane * 2) = o;
}

// ---------------------------------------------------------------- launch
extern "C" void kernel_launch(void* const* d_in, const int* in_sizes, int n_in,
                              void* d_out, int out_size, void* d_ws, size_t ws_size,
                              hipStream_t stream) {
    (void)in_sizes; (void)n_in; (void)out_size;
    Ptr7 feats;
    for (int i = 0; i < 7; i++) feats.p[i] = (const float*)d_in[i];
    const float* awq = (const float*)d_in[7];
    const float* abq = (const float*)d_in[8];
    const float* awk = (const float*)d_in[9];
    const float* abk = (const float*)d_in[10];
    const float* awv = (const float*)d_in[11];
    const float* abv = (const float*)d_in[12];
    const float* mw1 = (const float*)d_in[13];
    const float* mb1 = (const float*)d_in[14];
    const float* mw2 = (const float*)d_in[15];
    const float* mb2 = (const float*)d_in[16];
    const float* xyz = feats.p[0];

    char* ws = (char*)d_ws;
    size_t SZ_D = (size_t)BATCH * NPTS * NPTS * 4;           // 134,217,728
    size_t SZ_KV = (size_t)7 * BATCH * NPTS * CH * 4;        // 58,720,256
    size_t SZ_Q  = (size_t)7 * BATCH * NCEN * CH * 4;        // 14,680,064
    size_t SZ_O  = SZ_Q;
    size_t SZ_H  = (size_t)7 * BATCH * NCEN * CHO * 4;       // 29,360,128
    float* D = (float*)ws;
    size_t off = SZ_D;
    float* xx = (float*)(ws + off); off += (size_t)BATCH * NPTS * 4;
    unsigned* adjb = (unsigned*)(ws + off); off += (size_t)BATCH * NPTS * NW * 4;
    int* fpsidx = (int*)(ws + off); off += (size_t)BATCH * NCEN * 4;
    int* idxsel = (int*)(ws + off); off += (size_t)BATCH * NCEN * NNEI * 4;
    int* gatherC = (int*)(ws + off); off += (size_t)BATCH * NCEN * 4;
    float* qtab = (float*)(ws + off); off += SZ_Q;
    size_t base_off = off;

    // adaptive layout: separate ktab enables k-proj overlap with fps/top11
    bool kv_sep = (ws_size >= base_off + SZ_KV);
    float *ktab, *vtab, *otab, *htab;
    if (kv_sep) {
        ktab = (float*)(ws + base_off);
        // vtab/htab/otab overlay dead D after fused_mid: 58.7 + 29.4 + 14.7 = 102.8 <= 134.2 MB
        vtab = (float*)ws;
        htab = (float*)(ws + SZ_KV);
        otab = (float*)(ws + SZ_KV + SZ_H);
    } else {
        // fallback = round-20 layout (known to fit)
        ktab = (float*)ws;
        vtab = (float*)(ws + SZ_KV);
        otab = (float*)(ws + base_off);
        htab = (float*)(ws + base_off + SZ_O);
        if (ws_size < base_off + SZ_O + SZ_H) return;
    }

    xx_kernel<<<dim3((BATCH * NPTS + 255) / 256), dim3(256), 0, stream>>>(xyz, xx);
    dmat_kernel<<<dim3(NPTS / 64, NPTS / 64, BATCH), dim3(256), 0, stream>>>(xyz, xx, D);
    int front_blocks = BATCH + BATCH * NPTS + (kv_sep ? 7 * 2 * 256 : 0);
    fused_front_kernel<<<dim3(front_blocks), dim3(256), 0, stream>>>(D, adjb, fpsidx,
                                                                     feats, awk, abk, ktab);
    make_gather<<<dim3((BATCH * NCEN + 255) / 256), dim3(256), 0, stream>>>(fpsidx, gatherC);
    fused_mid_kernel<<<dim3(NCEN * BATCH + 2 * 7 * (BATCH * NCEN / 64)), dim3(256), 0, stream>>>(
        adjb, D, fpsidx, idxsel, feats, awq, abq, gatherC, qtab);
    // D dead after fused_mid
    if (kv_sep)
        vproj_kernel<<<dim3(BATCH * NPTS / 64, 2, 7), dim3(256), 0, stream>>>(feats, awv, abv, vtab);
    else
        kvproj_kernel<<<dim3(BATCH * NPTS / 64, 4, 7), dim3(256), 0, stream>>>(feats, awk, abk, awv, abv, ktab, vtab);
    attn_kernel<<<dim3(BATCH * NCEN / 4, 7), dim3(256), 0, stream>>>(qtab, ktab, vtab, idxsel, otab);
    mlp1_kernel<<<dim3(BATCH * NCEN / 64, 4, 7), dim3(256), 0, stream>>>(otab, mw1, mb1, htab);
    mlp2_kernel<<<dim3(BATCH * NCEN / 64, 4, 7), dim3(256), 0, stream>>>(htab, mw2, mb2, (float*)d_out);
}